// Round 1
// baseline (265.399 us; speedup 1.0000x reference)
//
#include <hip/hip_runtime.h>

// Performer feature map: out[row][m] = exp( sum_k x[row][k]/scale * W[m][k] ) / sqrt(M)
// rows = B*H*L = 262144, K = D = 128, N = M = 128. Memory-bound (32 FLOP/byte).
// bf16 MFMA compute; per-tile LDS-transposed epilogue for coalesced dwordx4 stores.
//
// R1 changes vs 226.8 us baseline:
//  - LDS 52224 -> 39936 B (Ob: per-wave 16x64 buffer -> 16x16 tile, pitch 20):
//    3 -> 4 blocks/CU, so all 1024 blocks co-resident (no 768+256 straggler round)
//    and 16 waves/CU for latency hiding. __launch_bounds__(256,4) pins it.
//  - dropped __builtin_nontemporal_load on x: each load instr touches 16B halves
//    of 64B sectors (pair completes it); nt no-allocate risks 2x HBM read
//    amplification. Plain loads let L2 assemble sectors. Stores keep nt.

typedef __attribute__((ext_vector_type(8))) short bf16x8;   // MFMA A/B frag (4 VGPRs)
typedef __attribute__((ext_vector_type(4))) float f32x4;    // MFMA C/D frag + 16B vec ld/st
typedef __attribute__((ext_vector_type(4))) short short4v;

#define WPITCH 136   // shorts; 272 B rows: b128 B-frag reads 16B-aligned, 2-way bank (free)
#define OPITCH 20    // floats; 80 B rows: b128 readback 16B-aligned, 2-way bank (free)

__device__ __forceinline__ short f2bf(float f) {
    // round-to-nearest-even fp32 -> bf16 (finite gaussian inputs; no NaN path)
    union { float f; unsigned u; } v; v.f = f;
    return (short)((v.u + 0x7fffu + ((v.u >> 16) & 1u)) >> 16);
}

__global__ __launch_bounds__(256, 4)
void performer_kernel(const float* __restrict__ x,
                      const float* __restrict__ Wf,
                      float* __restrict__ out,
                      int n_chunks) {   // chunk = 64 rows (4 waves x 16 rows)
    __shared__ short Wb[128 * WPITCH];        // 34816 B
    __shared__ float Ob[4 * 16 * OPITCH];     // 5120 B (per-wave 16x16 transpose tile)
    // total 39936 B <= 40960 -> 4 blocks/CU

    const int tid = threadIdx.x;

    // ---- Stage W -> LDS as bf16, scale 1/128^0.25 folded in. Coalesced float4 reads. ----
    {
        const float inv_scale = 0.29730177875068026f;  // 128^-0.25
        #pragma unroll
        for (int i = 0; i < 16; ++i) {
            int idx = i * 256 + tid;          // float4 index, 4096 total (128x128 fp32)
            int row = idx >> 5;
            int col = (idx & 31) << 2;
            f32x4 v = reinterpret_cast<const f32x4*>(Wf)[idx];
            short4v s;
            s.x = f2bf(v.x * inv_scale);
            s.y = f2bf(v.y * inv_scale);
            s.z = f2bf(v.z * inv_scale);
            s.w = f2bf(v.w * inv_scale);
            *reinterpret_cast<short4v*>(&Wb[row * WPITCH + col]) = s;
        }
    }
    __syncthreads();

    const int wave = tid >> 6;
    const int lane = tid & 63;
    const int m    = lane & 15;      // A-row within 16-tile; B-col within n-tile
    const int quad = lane >> 4;      // k-subblock select; C/D row group
    const int trow = lane >> 2;      // epilogue readback: row (4 lanes per row)
    const int tcol = (lane & 3) * 4; // epilogue readback: float4 column within 16
    float* obuf = &Ob[wave * 16 * OPITCH];
    const float inv_sqrt_m = 0.08838834764831845f;  // 1/sqrt(128)

    for (int chunk = blockIdx.x; chunk < n_chunks; chunk += gridDim.x) {
        const long row0 = (long)chunk * 64 + wave * 16;
        const float* xrow = x + (row0 + m) * 128 + quad * 8;

        // ---- A tile: 4 k-steps x 8 floats/lane (2x dwordx4, L2-cached: sector pairing) ----
        f32x4 av[4][2];
        #pragma unroll
        for (int ks = 0; ks < 4; ++ks) {
            const f32x4* p = reinterpret_cast<const f32x4*>(xrow + ks * 32);
            av[ks][0] = p[0];
            av[ks][1] = p[1];
        }
        bf16x8 af[4];
        #pragma unroll
        for (int ks = 0; ks < 4; ++ks) {
            af[ks][0] = f2bf(av[ks][0].x);
            af[ks][1] = f2bf(av[ks][0].y);
            af[ks][2] = f2bf(av[ks][0].z);
            af[ks][3] = f2bf(av[ks][0].w);
            af[ks][4] = f2bf(av[ks][1].x);
            af[ks][5] = f2bf(av[ks][1].y);
            af[ks][6] = f2bf(av[ks][1].z);
            af[ks][7] = f2bf(av[ks][1].w);
        }

        // ---- 8 n-tiles of 16 cols: MFMA accumulate ----
        f32x4 acc[8];
        #pragma unroll
        for (int nt = 0; nt < 8; ++nt) {
            f32x4 a = {0.f, 0.f, 0.f, 0.f};
            #pragma unroll
            for (int ks = 0; ks < 4; ++ks) {
                bf16x8 bf = *reinterpret_cast<const bf16x8*>(
                    &Wb[(nt * 16 + m) * WPITCH + ks * 32 + quad * 8]);
                a = __builtin_amdgcn_mfma_f32_16x16x32_bf16(af[ks], bf, a, 0, 0, 0);
            }
            acc[nt] = a;
        }

        // ---- Epilogue: exp, per-16x16-tile transpose through LDS, dwordx4 stores ----
        // C/D layout: col = lane&15 (=m), row = quad*4 + r.
        // Per store instr: 16 rows x 64 B contiguous aligned segments.
        float* orow = out + row0 * 128;
        #pragma unroll
        for (int nt = 0; nt < 8; ++nt) {
            #pragma unroll
            for (int r = 0; r < 4; ++r) {
                obuf[(quad * 4 + r) * OPITCH + m] =
                    __expf(acc[nt][r]) * inv_sqrt_m;
            }
            // same-wave LDS RAW/WAR: compiler inserts lgkmcnt waits
            f32x4 v = *reinterpret_cast<const f32x4*>(&obuf[trow * OPITCH + tcol]);
            __builtin_nontemporal_store(v, reinterpret_cast<f32x4*>(
                &orow[trow * 128 + nt * 16 + tcol]));
        }
    }
}

extern "C" void kernel_launch(void* const* d_in, const int* in_sizes, int n_in,
                              void* d_out, int out_size, void* d_ws, size_t ws_size,
                              hipStream_t stream) {
    const float* x  = (const float*)d_in[0];   // (B,H,L,D) fp32
    const float* Wf = (const float*)d_in[1];   // (M,D) fp32
    float* out = (float*)d_out;                // (B,H,L,M) fp32

    const int rows = out_size / 128;           // 262144
    const int n_chunks = rows / 64;            // 4096

    performer_kernel<<<dim3(1024), dim3(256), 0, stream>>>(x, Wf, out, n_chunks);
}

// Round 3
// 262.543 us; speedup vs baseline: 1.0109x; 1.0109x over previous
//
#include <hip/hip_runtime.h>

// Performer feature map: out[row][m] = exp( sum_k x[row][k]/scale * W[m][k] ) / sqrt(M)
// rows = B*H*L = 262144, K = D = 128, N = M = 128. Memory-bound (32 FLOP/byte).
//
// R2 (resubmit after container-side bench failure; no kernel change):
//   swapped-operand MFMA epilogue — no LDS transpose at all.
//   mfma(A=W-frag, B=X-frag): D col = lane&15 = x-row, D row = quad*4+r = feature.
//   Each lane holds 4 CONSECUTIVE features of one x-row -> direct f32x4 store.
//   Per store instr: 16 rows x 64 B contiguous (4 quads adjacent per row).
//   Stores are PLAIN (write-back): L2 sector dirty-masks assemble full lines,
//   avoiding R1's 1.64x partial-line nt-store write amplification (220->134 MB).
//   Ob buffer gone: LDS 39936 -> 34816 B, bank conflicts 1.57M -> ~0.

typedef __attribute__((ext_vector_type(8))) short bf16x8;   // MFMA A/B frag (4 VGPRs)
typedef __attribute__((ext_vector_type(4))) float f32x4;    // MFMA C/D frag + 16B vec ld/st
typedef __attribute__((ext_vector_type(4))) short short4v;

#define WPITCH 136   // shorts; 272 B rows: b128 W-frag reads 16B-aligned, 2-way bank (free)

__device__ __forceinline__ short f2bf(float f) {
    // round-to-nearest-even fp32 -> bf16 (finite gaussian inputs; no NaN path)
    union { float f; unsigned u; } v; v.f = f;
    return (short)((v.u + 0x7fffu + ((v.u >> 16) & 1u)) >> 16);
}

__global__ __launch_bounds__(256, 4)
void performer_kernel(const float* __restrict__ x,
                      const float* __restrict__ Wf,
                      float* __restrict__ out,
                      int n_chunks) {   // chunk = 64 rows (4 waves x 16 rows)
    __shared__ short Wb[128 * WPITCH];        // 34816 B -> 4 blocks/CU

    const int tid = threadIdx.x;

    // ---- Stage W -> LDS as bf16, scale 1/128^0.25 folded in. Coalesced float4 reads. ----
    {
        const float inv_scale = 0.29730177875068026f;  // 128^-0.25
        #pragma unroll
        for (int i = 0; i < 16; ++i) {
            int idx = i * 256 + tid;          // float4 index, 4096 total (128x128 fp32)
            int row = idx >> 5;
            int col = (idx & 31) << 2;
            f32x4 v = reinterpret_cast<const f32x4*>(Wf)[idx];
            short4v s;
            s.x = f2bf(v.x * inv_scale);
            s.y = f2bf(v.y * inv_scale);
            s.z = f2bf(v.z * inv_scale);
            s.w = f2bf(v.w * inv_scale);
            *reinterpret_cast<short4v*>(&Wb[row * WPITCH + col]) = s;
        }
    }
    __syncthreads();

    const int wave = tid >> 6;
    const int lane = tid & 63;
    const int m    = lane & 15;      // X-frag: x-row within 16-tile; W-frag: feature row
    const int quad = lane >> 4;      // k-subblock select; D row group (feature quad)
    const float inv_sqrt_m = 0.08838834764831845f;  // 1/sqrt(128)

    for (int chunk = blockIdx.x; chunk < n_chunks; chunk += gridDim.x) {
        const long row0 = (long)chunk * 64 + wave * 16;
        const float* xrow = x + (row0 + m) * 128 + quad * 8;

        // ---- X tile: 4 k-steps x 8 floats/lane (2x dwordx4; L2 pairs the 16B halves) ----
        f32x4 av[4][2];
        #pragma unroll
        for (int ks = 0; ks < 4; ++ks) {
            const f32x4* p = reinterpret_cast<const f32x4*>(xrow + ks * 32);
            av[ks][0] = p[0];
            av[ks][1] = p[1];
        }
        bf16x8 af[4];
        #pragma unroll
        for (int ks = 0; ks < 4; ++ks) {
            af[ks][0] = f2bf(av[ks][0].x);
            af[ks][1] = f2bf(av[ks][0].y);
            af[ks][2] = f2bf(av[ks][0].z);
            af[ks][3] = f2bf(av[ks][0].w);
            af[ks][4] = f2bf(av[ks][1].x);
            af[ks][5] = f2bf(av[ks][1].y);
            af[ks][6] = f2bf(av[ks][1].z);
            af[ks][7] = f2bf(av[ks][1].w);
        }

        // ---- 8 feature-tiles of 16: MFMA with SWAPPED operands (A=W, B=X) ----
        // D[feature][xrow]: col = lane&15 = xrow (matches af's row m),
        //                   row = quad*4+r = feature within tile.
        f32x4 acc[8];
        #pragma unroll
        for (int nt = 0; nt < 8; ++nt) {
            f32x4 a = {0.f, 0.f, 0.f, 0.f};
            #pragma unroll
            for (int ks = 0; ks < 4; ++ks) {
                bf16x8 wf = *reinterpret_cast<const bf16x8*>(
                    &Wb[(nt * 16 + m) * WPITCH + ks * 32 + quad * 8]);
                a = __builtin_amdgcn_mfma_f32_16x16x32_bf16(wf, af[ks], a, 0, 0, 0);
            }
            acc[nt] = a;
        }

        // ---- Epilogue: exp + direct f32x4 stores (lane owns 4 consecutive features
        //      of x-row m). Plain stores: L2 assembles the 64B segments into lines. ----
        float* orow = out + (row0 + m) * 128;
        #pragma unroll
        for (int nt = 0; nt < 8; ++nt) {
            f32x4 v;
            #pragma unroll
            for (int r = 0; r < 4; ++r)
                v[r] = __expf(acc[nt][r]) * inv_sqrt_m;
            *reinterpret_cast<f32x4*>(&orow[nt * 16 + quad * 4]) = v;
        }
    }
}

extern "C" void kernel_launch(void* const* d_in, const int* in_sizes, int n_in,
                              void* d_out, int out_size, void* d_ws, size_t ws_size,
                              hipStream_t stream) {
    const float* x  = (const float*)d_in[0];   // (B,H,L,D) fp32
    const float* Wf = (const float*)d_in[1];   // (M,D) fp32
    float* out = (float*)d_out;                // (B,H,L,M) fp32

    const int rows = out_size / 128;           // 262144
    const int n_chunks = rows / 64;            // 4096

    performer_kernel<<<dim3(1024), dim3(256), 0, stream>>>(x, Wf, out, n_chunks);
}